// Round 7
// baseline (247.564 us; speedup 1.0000x reference)
//
#include <hip/hip_runtime.h>
#include <hip/hip_bf16.h>
#include <math.h>

// ---------------------------------------------------------------------------
// TransformerLayer: B=2 S=2048 D=1024 H=16 HD=64. I/O f32, internals bf16.
// Round 7: (1) GEMM tile 128x128 (m97 geometry: 512B LDS per MFMA, was 768B),
// 2-phase dbuf, 1 barrier/step; (2) attention Q-tile 32 rows/wave (128/block)
// sharing K/V frags across both q-halves — halves staging+barriers per score.
// ---------------------------------------------------------------------------

#define B_ 2
#define S_ 2048
#define D_ 1024
#define H_ 16
#define HD_ 64

typedef __bf16 bf16_t;
typedef __bf16 bf16x8 __attribute__((ext_vector_type(8)));
typedef __bf16 bf16x4v __attribute__((ext_vector_type(4)));
typedef float f32x4 __attribute__((ext_vector_type(4)));

__device__ __forceinline__ f32x4 mfma16(bf16x8 a, bf16x8 b, f32x4 c) {
  return __builtin_amdgcn_mfma_f32_16x16x32_bf16(a, b, c, 0, 0, 0);
}

// global -> LDS direct copy, 16B/lane. LDS dest: wave-uniform base + lane*16.
__device__ __forceinline__ void gload_lds16(const bf16_t* g, bf16_t* l) {
  __builtin_amdgcn_global_load_lds((const __attribute__((address_space(1))) void*)g,
                                   (__attribute__((address_space(3))) void*)l,
                                   16, 0, 0);
}

// ---------------------------------------------------------------------------
// Kernel 0: convert 6 f32 weight matrices (D x D) to bf16, contiguous in dst.
// ---------------------------------------------------------------------------
__global__ __launch_bounds__(256) void cvtw_kernel(
    const float* __restrict__ w0, const float* __restrict__ w1,
    const float* __restrict__ w2, const float* __restrict__ w3,
    const float* __restrict__ w4, const float* __restrict__ w5,
    bf16_t* __restrict__ dst) {
  const int wsel = blockIdx.y;
  const float* src = wsel == 0 ? w0 : wsel == 1 ? w1 : wsel == 2 ? w2
                   : wsel == 3 ? w3 : wsel == 4 ? w4 : w5;
  const size_t off = (size_t)blockIdx.x * 1024 + threadIdx.x * 4;
  float4 v = *(const float4*)(src + off);
  bf16x4v r;
  r[0] = (bf16_t)v.x; r[1] = (bf16_t)v.y; r[2] = (bf16_t)v.z; r[3] = (bf16_t)v.w;
  *(bf16x4v*)(dst + (size_t)wsel * (D_ * D_) + off) = r;
}

// ---------------------------------------------------------------------------
// Kernel 1: positional encoding + add; f32 in -> bf16 out (q,k,v one pass).
// ---------------------------------------------------------------------------
__global__ __launch_bounds__(256) void addpe_kernel(
    const float* __restrict__ q, const float* __restrict__ k,
    const float* __restrict__ v,
    bf16_t* __restrict__ qo, bf16_t* __restrict__ ko, bf16_t* __restrict__ vo) {
  const int row = blockIdx.x;            // b*S + s
  const int s = row & (S_ - 1);
  const int d0 = threadIdx.x * 4;
  const size_t base = (size_t)row * D_ + d0;
  float pe[4];
#pragma unroll
  for (int p = 0; p < 2; ++p) {
    float div = __expf((float)(d0 + 2 * p) * -0.008994473019508f);
    float ang = (float)s * div;
    pe[2 * p]     = sinf(ang);
    pe[2 * p + 1] = cosf(ang);
  }
  float4 qv = *(const float4*)&q[base];
  float4 kv = *(const float4*)&k[base];
  float4 vv = *(const float4*)&v[base];
  bf16x4v qr, kr, vr;
  qr[0] = (bf16_t)(qv.x + pe[0]); qr[1] = (bf16_t)(qv.y + pe[1]);
  qr[2] = (bf16_t)(qv.z + pe[2]); qr[3] = (bf16_t)(qv.w + pe[3]);
  kr[0] = (bf16_t)(kv.x + pe[0]); kr[1] = (bf16_t)(kv.y + pe[1]);
  kr[2] = (bf16_t)(kv.z + pe[2]); kr[3] = (bf16_t)(kv.w + pe[3]);
  vr[0] = (bf16_t)(vv.x + pe[0]); vr[1] = (bf16_t)(vv.y + pe[1]);
  vr[2] = (bf16_t)(vv.z + pe[2]); vr[3] = (bf16_t)(vv.w + pe[3]);
  *(bf16x4v*)&qo[base] = qr;
  *(bf16x4v*)&ko[base] = kr;
  *(bf16x4v*)&vo[base] = vr;
}

// ---------------------------------------------------------------------------
// Kernel 2: NT GEMM C[M,N] = A[M,K] x W[N,K]^T, all bf16, m97 geometry:
// tile 128x128, BK=32, 4 waves (2x2, each 64x64 = 4x4 frags), 2-phase dbuf,
// 1 barrier/step, A and W staged via global_load_lds (4 issues/wave/step).
// MODE: 0 plain, 1 +bias, 2 +bias+relu, 3 QKV batched (z: 0=Q,1=K,2=V^T out)
// ---------------------------------------------------------------------------
template <int MODE>
__global__ __launch_bounds__(256) void gemm2p(
    const bf16_t* __restrict__ a0p, const bf16_t* __restrict__ a1p,
    const bf16_t* __restrict__ a2p,
    const bf16_t* __restrict__ w0p, const bf16_t* __restrict__ w1p,
    const bf16_t* __restrict__ w2p,
    const float* __restrict__ bias,
    bf16_t* __restrict__ o0, bf16_t* __restrict__ o1, bf16_t* __restrict__ o2) {
  constexpr int Kd = 1024, NT = Kd / 32;
  __shared__ alignas(16) bf16_t As[2][128 * 32];
  __shared__ alignas(16) bf16_t Bs[2][128 * 32];
  const int t = threadIdx.x, lane = t & 63, wid = t >> 6;
  const int g = lane >> 4, c16 = lane & 15;
  const int m0 = blockIdx.y * 128, n0 = blockIdx.x * 128;

  const bf16_t* A = a0p;
  const bf16_t* Wb = w0p;
  if (MODE == 3) {
    if (blockIdx.z == 1) { A = a1p; Wb = w1p; }
    else if (blockIdx.z == 2) { A = a2p; Wb = w2p; }
  }

  // staging: wave chunk = 16 rows x 32 cols; lane l -> row +l/4, col (l%4)*8
  const bf16_t* Asrc0 = A + (size_t)(m0 + wid * 16 + (lane >> 2)) * Kd + (lane & 3) * 8;
  const bf16_t* Asrc1 = Asrc0 + (size_t)64 * Kd;
  const bf16_t* Wsrc0 = Wb + (size_t)(n0 + wid * 16 + (lane >> 2)) * Kd + (lane & 3) * 8;
  const bf16_t* Wsrc1 = Wsrc0 + (size_t)64 * Kd;

  const f32x4 zero = {0.f, 0.f, 0.f, 0.f};
  f32x4 acc[4][4];
#pragma unroll
  for (int m = 0; m < 4; ++m)
#pragma unroll
    for (int n = 0; n < 4; ++n) acc[m][n] = zero;

  gload_lds16(Asrc0, &As[0][wid * 512]);
  gload_lds16(Asrc1, &As[0][2048 + wid * 512]);
  gload_lds16(Wsrc0, &Bs[0][wid * 512]);
  gload_lds16(Wsrc1, &Bs[0][2048 + wid * 512]);

  const int wr = wid >> 1, wc = wid & 1;
#pragma unroll 2
  for (int kt = 0; kt < NT; ++kt) {
    __syncthreads();                       // tile kt resident (vm drained)
    const int cur = kt & 1, nxt = cur ^ 1;
    if (kt + 1 < NT) {
      const int k0 = (kt + 1) * 32;
      gload_lds16(Asrc0 + k0, &As[nxt][wid * 512]);
      gload_lds16(Asrc1 + k0, &As[nxt][2048 + wid * 512]);
      gload_lds16(Wsrc0 + k0, &Bs[nxt][wid * 512]);
      gload_lds16(Wsrc1 + k0, &Bs[nxt][2048 + wid * 512]);
    }
    bf16x8 af[4], bfr[4];
#pragma unroll
    for (int m = 0; m < 4; ++m)
      af[m] = *(const bf16x8*)&As[cur][(wr * 64 + m * 16 + c16) * 32 + g * 8];
#pragma unroll
    for (int n = 0; n < 4; ++n)
      bfr[n] = *(const bf16x8*)&Bs[cur][(wc * 64 + n * 16 + c16) * 32 + g * 8];
#pragma unroll
    for (int m = 0; m < 4; ++m)
#pragma unroll
      for (int n = 0; n < 4; ++n)
        acc[m][n] = mfma16(af[m], bfr[n], acc[m][n]);
  }

  // epilogue: D frag: col = c16, row = g*4 + r
  const int rbase = m0 + wr * 64 + g * 4;
  const int cbase = n0 + wc * 64 + c16;
  if (MODE == 3 && blockIdx.z == 2) {
#pragma unroll
    for (int n = 0; n < 4; ++n) {
      const int col = cbase + n * 16;
#pragma unroll
      for (int m = 0; m < 4; ++m)
#pragma unroll
        for (int r = 0; r < 4; ++r) {
          const int row = rbase + m * 16 + r;
          const int bb = row >> 11, ss = row & (S_ - 1);
          o2[(size_t)bb * D_ * S_ + (size_t)col * S_ + ss] = (bf16_t)acc[m][n][r];
        }
    }
  } else {
    bf16_t* C = o0;
    if (MODE == 3 && blockIdx.z == 1) C = o1;
#pragma unroll
    for (int n = 0; n < 4; ++n) {
      const int col = cbase + n * 16;
      float bv = (MODE == 1 || MODE == 2) ? bias[col] : 0.f;
#pragma unroll
      for (int m = 0; m < 4; ++m)
#pragma unroll
        for (int r = 0; r < 4; ++r) {
          float vv = acc[m][n][r] + bv;
          if (MODE == 2) vv = fmaxf(vv, 0.f);
          C[(size_t)(rbase + m * 16 + r) * D_ + col] = (bf16_t)vv;
        }
    }
  }
}

// ---------------------------------------------------------------------------
// Kernel 3: flash attention. grid (S/128, B*H), 4 waves x 32 q-rows (2 halves
// of 16), KVBLK=64. K/V frag reads and staging shared across both q-halves.
// exp2-domain, defer-max (THR=11.54), l via MFMA-ones, swizzled K/Vt LDS.
// ---------------------------------------------------------------------------
__global__ __launch_bounds__(256) void attn_kernel(
    const bf16_t* __restrict__ Q, const bf16_t* __restrict__ K,
    const bf16_t* __restrict__ Vt, bf16_t* __restrict__ O) {
  constexpr int NT = S_ / 64;
  constexpr float THR = 11.5416f;          // 8 * log2(e)
  __shared__ alignas(16) bf16_t Ks[2][64 * 64];
  __shared__ alignas(16) bf16_t Vs[2][64 * 64];
  __shared__ alignas(16) bf16_t Ps[4 * 32 * 72];
  const int t = threadIdx.x, lane = t & 63, wid = t >> 6;
  const int b = blockIdx.y >> 4, h = blockIdx.y & 15;
  const int qw = blockIdx.x * 128 + wid * 32;   // this wave's 32 q-rows
  const int g = lane >> 4, c16 = lane & 15;

  // Q frags (A-op), two q-halves, pre-scaled into exp2 domain
  bf16x8 qa[2][2];
#pragma unroll
  for (int qh = 0; qh < 2; ++qh) {
    const size_t rowQ = (size_t)(b * S_ + qw + qh * 16 + c16) * D_ + h * HD_ + g * 8;
    qa[qh][0] = *(const bf16x8*)&Q[rowQ];
    qa[qh][1] = *(const bf16x8*)&Q[rowQ + 32];
#pragma unroll
    for (int j = 0; j < 8; ++j) {
      qa[qh][0][j] = (bf16_t)((float)qa[qh][0][j] * (0.125f * 1.44269504f));
      qa[qh][1][j] = (bf16_t)((float)qa[qh][1][j] * (0.125f * 1.44269504f));
    }
  }

  bf16x8 onesb;
#pragma unroll
  for (int j = 0; j < 8; ++j) onesb[j] = (bf16_t)1.0f;

  const f32x4 zero = {0.f, 0.f, 0.f, 0.f};
  f32x4 ctx[2][4] = {{zero, zero, zero, zero}, {zero, zero, zero, zero}};
  f32x4 lf[2] = {zero, zero};
  float mrow[2][4] = {{-1e30f, -1e30f, -1e30f, -1e30f},
                      {-1e30f, -1e30f, -1e30f, -1e30f}};

  // hoisted swizzled LDS read offsets (loop-invariant)
  int qk_addr[4][2];
#pragma unroll
  for (int kc = 0; kc < 4; ++kc) {
    const int krow = kc * 16 + c16;
    qk_addr[kc][0] = krow * 64 + ((0 + g) ^ (krow & 7)) * 8;
    qk_addr[kc][1] = krow * 64 + ((4 + g) ^ (krow & 7)) * 8;
  }
  int pv_vaddr[2][4];
#pragma unroll
  for (int ks = 0; ks < 2; ++ks)
#pragma unroll
    for (int n = 0; n < 4; ++n) {
      const int vrow = n * 16 + c16;
      pv_vaddr[ks][n] = vrow * 64 + ((ks * 4 + g) ^ (vrow & 7)) * 8;
    }
  bf16_t* const prb = &Ps[wid * 2304];     // this wave's P: [32 rows][72]

  // staging: wave w, chunk c covers tile-rows c*32 + w*8 + (lane>>3);
  // phys slot (lane&7) holds logical slot (lane&7)^(row&7)
  const int trow = wid * 8 + (lane >> 3);
  const int lslot = ((lane & 7) ^ ((lane >> 3) & 7)) * 8;
  const bf16_t* Ksrc0 = K + (size_t)(b * S_ + trow) * D_ + h * HD_ + lslot;
  const bf16_t* Ksrc1 = K + (size_t)(b * S_ + 32 + trow) * D_ + h * HD_ + lslot;
  const bf16_t* Vsrc0 = Vt + (size_t)b * D_ * S_ + (size_t)(h * HD_ + trow) * S_ + lslot;
  const bf16_t* Vsrc1 = Vt + (size_t)b * D_ * S_ + (size_t)(h * HD_ + 32 + trow) * S_ + lslot;

  gload_lds16(Ksrc0, &Ks[0][wid * 512]);
  gload_lds16(Ksrc1, &Ks[0][2048 + wid * 512]);
  gload_lds16(Vsrc0, &Vs[0][wid * 512]);
  gload_lds16(Vsrc1, &Vs[0][2048 + wid * 512]);

#pragma unroll 2
  for (int kt = 0; kt < NT; ++kt) {
    __syncthreads();                       // tile kt resident
    const int cur = kt & 1, nxt = cur ^ 1;
    if (kt + 1 < NT) {
      const size_t ko = (size_t)(kt + 1) * 64 * D_;
      gload_lds16(Ksrc0 + ko, &Ks[nxt][wid * 512]);
      gload_lds16(Ksrc1 + ko, &Ks[nxt][2048 + wid * 512]);
      const size_t vo = (size_t)(kt + 1) * 64;
      gload_lds16(Vsrc0 + vo, &Vs[nxt][wid * 512]);
      gload_lds16(Vsrc1 + vo, &Vs[nxt][2048 + wid * 512]);
    }

    // QK^T: 4 key-frags x 2 d-halves, kb shared by both q-halves
    f32x4 sf[2][4];
#pragma unroll
    for (int kc = 0; kc < 4; ++kc) {
      bf16x8 kb0 = *(const bf16x8*)&Ks[cur][qk_addr[kc][0]];
      bf16x8 kb1 = *(const bf16x8*)&Ks[cur][qk_addr[kc][1]];
#pragma unroll
      for (int qh = 0; qh < 2; ++qh) {
        f32x4 z = zero;
        z = mfma16(qa[qh][0], kb0, z);
        z = mfma16(qa[qh][1], kb1, z);
        sf[qh][kc] = z;
      }
    }

    // defer-max from unreduced per-lane maxima (wave-uniform decision)
    float lmx[2][4];
    bool needl = false;
#pragma unroll
    for (int qh = 0; qh < 2; ++qh)
#pragma unroll
      for (int r = 0; r < 4; ++r) {
        lmx[qh][r] = fmaxf(fmaxf(sf[qh][0][r], sf[qh][1][r]),
                           fmaxf(sf[qh][2][r], sf[qh][3][r]));
        needl |= (lmx[qh][r] > mrow[qh][r] + THR);
      }
    if (__any(needl)) {
#pragma unroll
      for (int qh = 0; qh < 2; ++qh)
#pragma unroll
        for (int r = 0; r < 4; ++r) {
          float mx = lmx[qh][r];
#pragma unroll
          for (int o = 1; o < 16; o <<= 1) mx = fmaxf(mx, __shfl_xor(mx, o));
          float mnew = fmaxf(mrow[qh][r], mx);
          float scl = exp2f(mrow[qh][r] - mnew);
          lf[qh][r] *= scl;
#pragma unroll
          for (int n = 0; n < 4; ++n) ctx[qh][n][r] *= scl;
          mrow[qh][r] = mnew;
        }
    }

    // P = exp2(s - m) -> padded LDS (row = 16*qh + g*4 + r, col = key)
#pragma unroll
    for (int qh = 0; qh < 2; ++qh)
#pragma unroll
      for (int r = 0; r < 4; ++r) {
        bf16_t* pr = prb + (qh * 16 + g * 4 + r) * 72 + c16;
        pr[0]  = (bf16_t)exp2f(sf[qh][0][r] - mrow[qh][r]);
        pr[16] = (bf16_t)exp2f(sf[qh][1][r] - mrow[qh][r]);
        pr[32] = (bf16_t)exp2f(sf[qh][2][r] - mrow[qh][r]);
        pr[48] = (bf16_t)exp2f(sf[qh][3][r] - mrow[qh][r]);
      }

    // PV + l: A = P frags (per q-half), B = V^T frags shared across halves
#pragma unroll
    for (int ks = 0; ks < 2; ++ks) {
      bf16x8 ap[2];
#pragma unroll
      for (int qh = 0; qh < 2; ++qh) {
        ap[qh] = *(const bf16x8*)&prb[(qh * 16 + c16) * 72 + ks * 32 + g * 8];
        lf[qh] = mfma16(ap[qh], onesb, lf[qh]);
      }
#pragma unroll
      for (int n = 0; n < 4; ++n) {
        bf16x8 vb = *(const bf16x8*)&Vs[cur][pv_vaddr[ks][n]];
#pragma unroll
        for (int qh = 0; qh < 2; ++qh)
          ctx[qh][n] = mfma16(ap[qh], vb, ctx[qh][n]);
      }
    }
  }

  // write (D-frag: row = g*4+r within half, col = n*16+c16)
#pragma unroll
  for (int qh = 0; qh < 2; ++qh)
#pragma unroll
    for (int r = 0; r < 4; ++r) {
      float inv = 1.f / lf[qh][r];
      const size_t ro = (size_t)(b * S_ + qw + qh * 16 + g * 4 + r) * D_ + h * HD_ + c16;
#pragma unroll
      for (int n = 0; n < 4; ++n)
        O[ro + n * 16] = (bf16_t)(ctx[qh][n][r] * inv);
    }
}

// ---------------------------------------------------------------------------
// Kernel 4: out = LayerNorm(a + res) * g + b.  a,res bf16; g,b f32.
// ---------------------------------------------------------------------------
template <typename OUT>
__global__ __launch_bounds__(256) void add_ln_kernel(
    const bf16_t* __restrict__ a, const bf16_t* __restrict__ res,
    const float* __restrict__ g, const float* __restrict__ be,
    OUT* __restrict__ out) {
  const int t = threadIdx.x;
  const int d0 = t * 4;
  const size_t base = (size_t)blockIdx.x * D_ + d0;
  float x[4];
  float s1 = 0.f, s2 = 0.f;
#pragma unroll
  for (int e = 0; e < 4; ++e) {
    x[e] = (float)a[base + e] + (float)res[base + e];
    s1 += x[e];
    s2 += x[e] * x[e];
  }
#pragma unroll
  for (int o = 32; o > 0; o >>= 1) {
    s1 += __shfl_down(s1, o);
    s2 += __shfl_down(s2, o);
  }
  __shared__ float red[8];
  const int lane = t & 63, wid = t >> 6;
  if (lane == 0) { red[wid] = s1; red[4 + wid] = s2; }
  __syncthreads();
  if (t == 0) {
    float t1 = red[0] + red[1] + red[2] + red[3];
    float t2 = red[4] + red[5] + red[6] + red[7];
    float mu = t1 * (1.f / D_);
    float var = t2 * (1.f / D_) - mu * mu;
    red[0] = mu;
    red[1] = rsqrtf(var + 1e-5f);
  }
  __syncthreads();
  const float mu = red[0], rstd = red[1];
#pragma unroll
  for (int e = 0; e < 4; ++e)
    out[base + e] = (OUT)((x[e] - mu) * rstd * g[d0 + e] + be[d0 + e]);
}

// ---------------------------------------------------------------------------
extern "C" void kernel_launch(void* const* d_in, const int* in_sizes, int n_in,
                              void* d_out, int out_size, void* d_ws, size_t ws_size,
                              hipStream_t stream) {
  const float* key   = (const float*)d_in[0];
  const float* value = (const float*)d_in[1];
  const float* query = (const float*)d_in[2];
  const float* Wq = (const float*)d_in[3];
  const float* Wk = (const float*)d_in[4];
  const float* Wv = (const float*)d_in[5];
  const float* Wo = (const float*)d_in[6];
  const float* W1 = (const float*)d_in[7];
  const float* b1 = (const float*)d_in[8];
  const float* W2 = (const float*)d_in[9];
  const float* b2 = (const float*)d_in[10];
  const float* g1 = (const float*)d_in[11];
  const float* be1 = (const float*)d_in[12];
  const float* g2 = (const float*)d_in[13];
  const float* be2 = (const float*)d_in[14];
  float* out = (float*)d_out;

  bf16_t* ws = (bf16_t*)d_ws;
  const size_t NB = (size_t)B_ * S_ * D_;  // 4 Mi elems
  bf16_t* qpe = ws + 0 * NB;
  bf16_t* kpe = ws + 1 * NB;
  bf16_t* vpe = ws + 2 * NB;
  bf16_t* Qp  = ws + 3 * NB;
  bf16_t* Kp  = ws + 4 * NB;
  bf16_t* Vt  = ws + 5 * NB;   // [B][D][S] transposed V projection
  bf16_t* ctx = kpe;  // dead after QKV gemm
  bf16_t* ao  = vpe;  // dead after QKV gemm
  bf16_t* x1  = Qp;   // dead after attention
  bf16_t* hh  = Kp;   // dead after attention
  bf16_t* ff  = Vt;   // dead after attention

  // bf16 weights live in d_out (16 MB; 6 x 2 MB used, overwritten by final LN)
  bf16_t* wb = (bf16_t*)d_out;
  const size_t WN = (size_t)D_ * D_;
  bf16_t* Wqb = wb + 0 * WN;
  bf16_t* Wkb = wb + 1 * WN;
  bf16_t* Wvb = wb + 2 * WN;
  bf16_t* Wob = wb + 3 * WN;
  bf16_t* W1b = wb + 4 * WN;
  bf16_t* W2b = wb + 5 * WN;

  dim3 ggrid(D_ / 128, (B_ * S_) / 128);       // 8 x 32 = 256

  cvtw_kernel<<<dim3(D_ * D_ / 1024, 6), 256, 0, stream>>>(
      Wq, Wk, Wv, Wo, W1, W2, wb);
  addpe_kernel<<<B_ * S_, 256, 0, stream>>>(query, key, value, qpe, kpe, vpe);

  gemm2p<3><<<dim3(D_ / 128, (B_ * S_) / 128, 3), 256, 0, stream>>>(
      qpe, kpe, vpe, Wqb, Wkb, Wvb, nullptr, Qp, Kp, Vt);

  attn_kernel<<<dim3(S_ / 128, B_ * H_), 256, 0, stream>>>(Qp, Kp, Vt, ctx);

  gemm2p<0><<<ggrid, 256, 0, stream>>>(ctx, nullptr, nullptr, Wob, nullptr, nullptr,
                                       nullptr, ao, nullptr, nullptr);
  add_ln_kernel<bf16_t><<<B_ * S_, 256, 0, stream>>>(ao, qpe, g1, be1, x1);

  gemm2p<2><<<ggrid, 256, 0, stream>>>(x1, nullptr, nullptr, W1b, nullptr, nullptr,
                                       b1, hh, nullptr, nullptr);
  gemm2p<1><<<ggrid, 256, 0, stream>>>(hh, nullptr, nullptr, W2b, nullptr, nullptr,
                                       b2, ff, nullptr, nullptr);
  add_ln_kernel<float><<<B_ * S_, 256, 0, stream>>>(ff, x1, g2, be2, out);
}

// Round 8
// 242.516 us; speedup vs baseline: 1.0208x; 1.0208x over previous
//
#include <hip/hip_runtime.h>
#include <hip/hip_bf16.h>
#include <math.h>

// ---------------------------------------------------------------------------
// TransformerLayer: B=2 S=2048 D=1024 H=16 HD=64. I/O f32, internals bf16.
// Round 8: attention rewritten to swapped-operand 32x32 MFMA structure
// (S^T = mfma(K,Q): scores lane-local per q-row; softmax scalar; P stays in
// registers via cvt_pk + shfl_xor(32) — NO P LDS round-trip; l via mfma-ones
// in crow layout). Singles GEMM reverted to 128x64 (2 blocks/CU); QKV at 128².
// ---------------------------------------------------------------------------

#define B_ 2
#define S_ 2048
#define D_ 1024
#define H_ 16
#define HD_ 64

typedef __bf16 bf16_t;
typedef __bf16 bf16x8 __attribute__((ext_vector_type(8)));
typedef __bf16 bf16x4v __attribute__((ext_vector_type(4)));
typedef float f32x4 __attribute__((ext_vector_type(4)));
typedef float f32x16 __attribute__((ext_vector_type(16)));
typedef unsigned int u32;

__device__ __forceinline__ f32x4 mfma16(bf16x8 a, bf16x8 b, f32x4 c) {
  return __builtin_amdgcn_mfma_f32_16x16x32_bf16(a, b, c, 0, 0, 0);
}
__device__ __forceinline__ f32x16 mfma32(bf16x8 a, bf16x8 b, f32x16 c) {
  return __builtin_amdgcn_mfma_f32_32x32x16_bf16(a, b, c, 0, 0, 0);
}
__device__ __forceinline__ u32 pkbf(float a, float b) {
  union { bf16_t h[2]; u32 u; } t;
  t.h[0] = (bf16_t)a; t.h[1] = (bf16_t)b;
  return t.u;
}

// global -> LDS direct copy, 16B/lane. LDS dest: wave-uniform base + lane*16.
__device__ __forceinline__ void gload_lds16(const bf16_t* g, bf16_t* l) {
  __builtin_amdgcn_global_load_lds((const __attribute__((address_space(1))) void*)g,
                                   (__attribute__((address_space(3))) void*)l,
                                   16, 0, 0);
}

// ---------------------------------------------------------------------------
// Kernel 0: convert 6 f32 weight matrices (D x D) to bf16, contiguous in dst.
// ---------------------------------------------------------------------------
__global__ __launch_bounds__(256) void cvtw_kernel(
    const float* __restrict__ w0, const float* __restrict__ w1,
    const float* __restrict__ w2, const float* __restrict__ w3,
    const float* __restrict__ w4, const float* __restrict__ w5,
    bf16_t* __restrict__ dst) {
  const int wsel = blockIdx.y;
  const float* src = wsel == 0 ? w0 : wsel == 1 ? w1 : wsel == 2 ? w2
                   : wsel == 3 ? w3 : wsel == 4 ? w4 : w5;
  const size_t off = (size_t)blockIdx.x * 1024 + threadIdx.x * 4;
  float4 v = *(const float4*)(src + off);
  bf16x4v r;
  r[0] = (bf16_t)v.x; r[1] = (bf16_t)v.y; r[2] = (bf16_t)v.z; r[3] = (bf16_t)v.w;
  *(bf16x4v*)(dst + (size_t)wsel * (D_ * D_) + off) = r;
}

// ---------------------------------------------------------------------------
// Kernel 1: positional encoding + add; f32 in -> bf16 out (q,k,v one pass).
// ---------------------------------------------------------------------------
__global__ __launch_bounds__(256) void addpe_kernel(
    const float* __restrict__ q, const float* __restrict__ k,
    const float* __restrict__ v,
    bf16_t* __restrict__ qo, bf16_t* __restrict__ ko, bf16_t* __restrict__ vo) {
  const int row = blockIdx.x;            // b*S + s
  const int s = row & (S_ - 1);
  const int d0 = threadIdx.x * 4;
  const size_t base = (size_t)row * D_ + d0;
  float pe[4];
#pragma unroll
  for (int p = 0; p < 2; ++p) {
    float div = __expf((float)(d0 + 2 * p) * -0.008994473019508f);
    float ang = (float)s * div;
    pe[2 * p]     = sinf(ang);
    pe[2 * p + 1] = cosf(ang);
  }
  float4 qv = *(const float4*)&q[base];
  float4 kv = *(const float4*)&k[base];
  float4 vv = *(const float4*)&v[base];
  bf16x4v qr, kr, vr;
  qr[0] = (bf16_t)(qv.x + pe[0]); qr[1] = (bf16_t)(qv.y + pe[1]);
  qr[2] = (bf16_t)(qv.z + pe[2]); qr[3] = (bf16_t)(qv.w + pe[3]);
  kr[0] = (bf16_t)(kv.x + pe[0]); kr[1] = (bf16_t)(kv.y + pe[1]);
  kr[2] = (bf16_t)(kv.z + pe[2]); kr[3] = (bf16_t)(kv.w + pe[3]);
  vr[0] = (bf16_t)(vv.x + pe[0]); vr[1] = (bf16_t)(vv.y + pe[1]);
  vr[2] = (bf16_t)(vv.z + pe[2]); vr[3] = (bf16_t)(vv.w + pe[3]);
  *(bf16x4v*)&qo[base] = qr;
  *(bf16x4v*)&ko[base] = kr;
  *(bf16x4v*)&vo[base] = vr;
}

// ---------------------------------------------------------------------------
// Kernel 2a: singles NT GEMM, tile 128x64 (grid 512 = 2 blocks/CU), BK=32,
// 4 waves (2x2, each 64x32), 2-phase dbuf, all-gload_lds.  (round-6 verified)
// EPI: 0 plain, 1 +bias, 2 +bias+relu
// ---------------------------------------------------------------------------
template <int EPI>
__global__ __launch_bounds__(256) void gemm_s(
    const bf16_t* __restrict__ A, const bf16_t* __restrict__ Wb,
    const float* __restrict__ bias, bf16_t* __restrict__ C) {
  constexpr int Kd = 1024, NT = Kd / 32;
  __shared__ alignas(16) bf16_t As[2][128 * 32];
  __shared__ alignas(16) bf16_t Bs[2][64 * 32];
  const int t = threadIdx.x, lane = t & 63, wid = t >> 6;
  const int m0 = blockIdx.y * 128, n0 = blockIdx.x * 64;

  const bf16_t* Asrc0 = A + (size_t)(m0 + wid * 16 + (lane >> 2)) * Kd + (lane & 3) * 8;
  const bf16_t* Asrc1 = Asrc0 + (size_t)64 * Kd;
  const bf16_t* Wsrc = Wb + (size_t)(n0 + wid * 16 + (lane >> 2)) * Kd + (lane & 3) * 8;

  const f32x4 zero = {0.f, 0.f, 0.f, 0.f};
  f32x4 acc[4][2];
#pragma unroll
  for (int m = 0; m < 4; ++m) { acc[m][0] = zero; acc[m][1] = zero; }

  gload_lds16(Asrc0, &As[0][wid * 512]);
  gload_lds16(Asrc1, &As[0][2048 + wid * 512]);
  gload_lds16(Wsrc,  &Bs[0][wid * 512]);

  const int wr = wid >> 1, wc = wid & 1;
#pragma unroll 2
  for (int kt = 0; kt < NT; ++kt) {
    __syncthreads();
    const int cur = kt & 1, nxt = cur ^ 1;
    if (kt + 1 < NT) {
      const int k0 = (kt + 1) * 32;
      gload_lds16(Asrc0 + k0, &As[nxt][wid * 512]);
      gload_lds16(Asrc1 + k0, &As[nxt][2048 + wid * 512]);
      gload_lds16(Wsrc + k0,  &Bs[nxt][wid * 512]);
    }
    bf16x8 af[4], bfr[2];
#pragma unroll
    for (int m = 0; m < 4; ++m)
      af[m] = *(const bf16x8*)&As[cur][(wr * 64 + m * 16 + (lane & 15)) * 32 + (lane >> 4) * 8];
#pragma unroll
    for (int n = 0; n < 2; ++n)
      bfr[n] = *(const bf16x8*)&Bs[cur][(wc * 32 + n * 16 + (lane & 15)) * 32 + (lane >> 4) * 8];
#pragma unroll
    for (int m = 0; m < 4; ++m)
#pragma unroll
      for (int n = 0; n < 2; ++n)
        acc[m][n] = mfma16(af[m], bfr[n], acc[m][n]);
  }

  const int rbase = m0 + wr * 64 + (lane >> 4) * 4;
  const int cbase = n0 + wc * 32 + (lane & 15);
#pragma unroll
  for (int n = 0; n < 2; ++n) {
    const int col = cbase + n * 16;
    float bv = (EPI >= 1) ? bias[col] : 0.f;
#pragma unroll
    for (int m = 0; m < 4; ++m)
#pragma unroll
      for (int r = 0; r < 4; ++r) {
        float vv = acc[m][n][r] + bv;
        if (EPI == 2) vv = fmaxf(vv, 0.f);
        C[(size_t)(rbase + m * 16 + r) * D_ + col] = (bf16_t)vv;
      }
  }
}

// ---------------------------------------------------------------------------
// Kernel 2b: QKV batched GEMM, tile 128x128 (grid 768 = 3 blocks/CU), BK=32,
// 4 waves (2x2, each 64x64), 2-phase dbuf. z: 0=Q, 1=K, 2=V^T out.
// ---------------------------------------------------------------------------
__global__ __launch_bounds__(256) void gemm_qkv(
    const bf16_t* __restrict__ a0p, const bf16_t* __restrict__ a1p,
    const bf16_t* __restrict__ a2p,
    const bf16_t* __restrict__ w0p, const bf16_t* __restrict__ w1p,
    const bf16_t* __restrict__ w2p,
    bf16_t* __restrict__ o0, bf16_t* __restrict__ o1, bf16_t* __restrict__ o2) {
  constexpr int Kd = 1024, NT = Kd / 32;
  __shared__ alignas(16) bf16_t As[2][128 * 32];
  __shared__ alignas(16) bf16_t Bs[2][128 * 32];
  const int t = threadIdx.x, lane = t & 63, wid = t >> 6;
  const int g = lane >> 4, c16 = lane & 15;
  const int m0 = blockIdx.y * 128, n0 = blockIdx.x * 128;

  const bf16_t* A = a0p;
  const bf16_t* Wb = w0p;
  if (blockIdx.z == 1) { A = a1p; Wb = w1p; }
  else if (blockIdx.z == 2) { A = a2p; Wb = w2p; }

  const bf16_t* Asrc0 = A + (size_t)(m0 + wid * 16 + (lane >> 2)) * Kd + (lane & 3) * 8;
  const bf16_t* Asrc1 = Asrc0 + (size_t)64 * Kd;
  const bf16_t* Wsrc0 = Wb + (size_t)(n0 + wid * 16 + (lane >> 2)) * Kd + (lane & 3) * 8;
  const bf16_t* Wsrc1 = Wsrc0 + (size_t)64 * Kd;

  const f32x4 zero = {0.f, 0.f, 0.f, 0.f};
  f32x4 acc[4][4];
#pragma unroll
  for (int m = 0; m < 4; ++m)
#pragma unroll
    for (int n = 0; n < 4; ++n) acc[m][n] = zero;

  gload_lds16(Asrc0, &As[0][wid * 512]);
  gload_lds16(Asrc1, &As[0][2048 + wid * 512]);
  gload_lds16(Wsrc0, &Bs[0][wid * 512]);
  gload_lds16(Wsrc1, &Bs[0][2048 + wid * 512]);

  const int wr = wid >> 1, wc = wid & 1;
#pragma unroll 2
  for (int kt = 0; kt < NT; ++kt) {
    __syncthreads();
    const int cur = kt & 1, nxt = cur ^ 1;
    if (kt + 1 < NT) {
      const int k0 = (kt + 1) * 32;
      gload_lds16(Asrc0 + k0, &As[nxt][wid * 512]);
      gload_lds16(Asrc1 + k0, &As[nxt][2048 + wid * 512]);
      gload_lds16(Wsrc0 + k0, &Bs[nxt][wid * 512]);
      gload_lds16(Wsrc1 + k0, &Bs[nxt][2048 + wid * 512]);
    }
    bf16x8 af[4], bfr[4];
#pragma unroll
    for (int m = 0; m < 4; ++m)
      af[m] = *(const bf16x8*)&As[cur][(wr * 64 + m * 16 + c16) * 32 + g * 8];
#pragma unroll
    for (int n = 0; n < 4; ++n)
      bfr[n] = *(const bf16x8*)&Bs[cur][(wc * 64 + n * 16 + c16) * 32 + g * 8];
#pragma unroll
    for (int m = 0; m < 4; ++m)
#pragma unroll
      for (int n = 0; n < 4; ++n)
        acc[m][n] = mfma16(af[m], bfr[n], acc[m][n]);
  }

  const int rbase = m0 + wr * 64 + g * 4;
  const int cbase = n0 + wc * 64 + c16;
  if (blockIdx.z == 2) {
#pragma unroll
    for (int n = 0; n < 4; ++n) {
      const int col = cbase + n * 16;
#pragma unroll
      for (int m = 0; m < 4; ++m)
#pragma unroll
        for (int r = 0; r < 4; ++r) {
          const int row = rbase + m * 16 + r;
          const int bb = row >> 11, ss = row & (S_ - 1);
          o2[(size_t)bb * D_ * S_ + (size_t)col * S_ + ss] = (bf16_t)acc[m][n][r];
        }
    }
  } else {
    bf16_t* C = (blockIdx.z == 1) ? o1 : o0;
#pragma unroll
    for (int n = 0; n < 4; ++n) {
      const int col = cbase + n * 16;
#pragma unroll
      for (int m = 0; m < 4; ++m)
#pragma unroll
        for (int r = 0; r < 4; ++r)
          C[(size_t)(rbase + m * 16 + r) * D_ + col] = (bf16_t)acc[m][n][r];
    }
  }
}

// ---------------------------------------------------------------------------
// Kernel 3: flash attention, swapped-operand 32x32 structure.
// grid (S/128, B*H), 4 waves x 32 q-rows, KVBLK=64.
// S^T = mfma32(K,Q): lane (q=lane&31, hi=lane>>5) holds S[key=crow(reg,hi)][q]
// for 2 key-chunks; softmax lane-local (31 fmax + 1 shfl_xor(32)); P->bf16
// in-register (pkbf pairs + shfl_xor(32) exchange) feeds PV A-frags directly.
// l via mfma-ones (crow layout = ctx layout). K/Vt swizzled gload_lds, dbuf.
// ---------------------------------------------------------------------------
__global__ __launch_bounds__(256) void attn_kernel(
    const bf16_t* __restrict__ Q, const bf16_t* __restrict__ K,
    const bf16_t* __restrict__ Vt, bf16_t* __restrict__ O) {
  constexpr int NT = S_ / 64;
  constexpr float THR = 11.5416f;          // 8 * log2(e)
  __shared__ alignas(16) bf16_t Ks[2][64 * 64];
  __shared__ alignas(16) bf16_t Vs[2][64 * 64];
  const int t = threadIdx.x, lane = t & 63, wid = t >> 6;
  const int b = blockIdx.y >> 4, h = blockIdx.y & 15;
  const int qw = blockIdx.x * 128 + wid * 32;   // this wave's 32 q-rows
  const int q31 = lane & 31, hi = lane >> 5;

  // Q as B-operand frags: col=lane&31=q, k=hi*8+j = d within 16-slice.
  bf16x8 qb[4];
  {
    const size_t qrow = (size_t)(b * S_ + qw + q31) * D_ + h * HD_ + hi * 8;
#pragma unroll
    for (int ksl = 0; ksl < 4; ++ksl) {
      bf16x8 v = *(const bf16x8*)&Q[qrow + ksl * 16];
#pragma unroll
      for (int j = 0; j < 8; ++j)
        v[j] = (bf16_t)((float)v[j] * (0.125f * 1.44269504f));
      qb[ksl] = v;
    }
  }
  bf16x8 onesb;
#pragma unroll
  for (int j = 0; j < 8; ++j) onesb[j] = (bf16_t)1.0f;

  f32x16 ctx0 = {0.f,0.f,0.f,0.f,0.f,0.f,0.f,0.f,0.f,0.f,0.f,0.f,0.f,0.f,0.f,0.f};
  f32x16 ctx1 = ctx0, lf = ctx0;
  float mrow = -1e30f;

  // swizzled LDS read slots: slot x at row r -> phys ((x)^(r&7))*8; rows used
  // are (chunk*32 + q31) so r&7 == q31&7 for both chunks.
  int sw[4];
#pragma unroll
  for (int x = 0; x < 4; ++x) sw[x] = ((x * 2 + hi) ^ (q31 & 7)) * 8;

  // staging (same as r7): wave w, chunk c covers tile-rows c*32+w*8+(lane>>3);
  // phys slot (lane&7) holds logical slot (lane&7)^(row&7)
  const int trow = wid * 8 + (lane >> 3);
  const int lslot = ((lane & 7) ^ ((lane >> 3) & 7)) * 8;
  const bf16_t* Ksrc0 = K + (size_t)(b * S_ + trow) * D_ + h * HD_ + lslot;
  const bf16_t* Ksrc1 = K + (size_t)(b * S_ + 32 + trow) * D_ + h * HD_ + lslot;
  const bf16_t* Vsrc0 = Vt + (size_t)b * D_ * S_ + (size_t)(h * HD_ + trow) * S_ + lslot;
  const bf16_t* Vsrc1 = Vt + (size_t)b * D_ * S_ + (size_t)(h * HD_ + 32 + trow) * S_ + lslot;

  gload_lds16(Ksrc0, &Ks[0][wid * 512]);
  gload_lds16(Ksrc1, &Ks[0][2048 + wid * 512]);
  gload_lds16(Vsrc0, &Vs[0][wid * 512]);
  gload_lds16(Vsrc1, &Vs[0][2048 + wid * 512]);

#pragma unroll 2
  for (int kt = 0; kt < NT; ++kt) {
    __syncthreads();                       // tile kt resident
    const int cur = kt & 1, nxt = cur ^ 1;
    if (kt + 1 < NT) {
      const size_t ko = (size_t)(kt + 1) * 64 * D_;
      gload_lds16(Ksrc0 + ko, &Ks[nxt][wid * 512]);
      gload_lds16(Ksrc1 + ko, &Ks[nxt][2048 + wid * 512]);
      const size_t vo = (size_t)(kt + 1) * 64;
      gload_lds16(Vsrc0 + vo, &Vs[nxt][wid * 512]);
      gload_lds16(Vsrc1 + vo, &Vs[nxt][2048 + wid * 512]);
    }

    // QK^T swapped: s0 = S^T keys 0..31, s1 = keys 32..63 (rows=key, col=q)
    f32x16 s0 = {0.f,0.f,0.f,0.f,0.f,0.f,0.f,0.f,0.f,0.f,0.f,0.f,0.f,0.f,0.f,0.f};
    f32x16 s1 = s0;
#pragma unroll
    for (int ksl = 0; ksl < 4; ++ksl) {
      bf16x8 kb0 = *(const bf16x8*)&Ks[cur][q31 * 64 + sw[ksl]];
      bf16x8 kb1 = *(const bf16x8*)&Ks[cur][(32 + q31) * 64 + sw[ksl]];
      s0 = mfma32(kb0, qb[ksl], s0);
      s1 = mfma32(kb1, qb[ksl], s1);
    }

    // lane-local softmax for q = lane&31 (keys split with partner lane^32)
    float mt = fmaxf(s0[0], s1[0]);
#pragma unroll
    for (int r = 1; r < 16; ++r) mt = fmaxf(mt, fmaxf(s0[r], s1[r]));
    mt = fmaxf(mt, __shfl_xor(mt, 32));
    if (__any(mt > mrow + THR)) {
      float mnew = fmaxf(mrow, mt);
      float scl = exp2f(mrow - mnew);
      mrow = mnew;
#pragma unroll
      for (int r = 0; r < 16; ++r) {
        float sc = __shfl(scl, (r & 3) + 8 * (r >> 2) + 4 * hi);
        ctx0[r] *= sc; ctx1[r] *= sc; lf[r] *= sc;
      }
    }
    // P = exp2(s - m) in place
#pragma unroll
    for (int r = 0; r < 16; ++r) {
      s0[r] = exp2f(s0[r] - mrow);
      s1[r] = exp2f(s1[r] - mrow);
    }

    // build PV A-frags in-register: pa[ks][j2*4+j1] =
    //   P[q][ks*16+hi*8+j] = p[ks>>1][reg 4*((ks&1)*2+hi)+j1] from half j2
    bf16x8 pa[4];
#pragma unroll
    for (int ks = 0; ks < 4; ++ks) {
      const int e = ks & 1;
      u32 A0, A1, B0, B1;
      if (ks < 2) {
        A0 = pkbf(s0[8 * e + 0], s0[8 * e + 1]);
        A1 = pkbf(s0[8 * e + 2], s0[8 * e + 3]);
        B0 = pkbf(s0[8 * e + 4], s0[8 * e + 5]);
        B1 = pkbf(s0[8 * e + 6], s0[8 * e + 7]);
      } else {
        A0 = pkbf(s1[8 * e + 0], s1[8 * e + 1]);
        A1 = pkbf(s1[8 * e + 2], s1[8 * e + 3]);
        B0 = pkbf(s1[8 * e + 4], s1[8 * e + 5]);
        B1 = pkbf(s1[8 * e + 6], s1[8 * e + 7]);
      }
      u32 T0 = hi ? A0 : B0;           // what the partner half needs from us
      u32 T1 = hi ? A1 : B1;
      u32 X0 = (u32)__shfl_xor((int)T0, 32);
      u32 X1 = (u32)__shfl_xor((int)T1, 32);
      union { u32 w[4]; bf16x8 v; } u;
      u.w[0] = hi ? X0 : A0;           // j=0,1  (source half 0)
      u.w[1] = hi ? X1 : A1;           // j=2,3
      u.w[2] = hi ? B0 : X0;           // j=4,5  (source half 1)
      u.w[3] = hi ? B1 : X1;           // j=6,7
      pa[ks] = u.v;
    }

    // l and PV: rows = q (crow layout), cols = d
#pragma unroll
    for (int ks = 0; ks < 4; ++ks) lf = mfma32(pa[ks], onesb, lf);
#pragma unroll
    for (int ks = 0; ks < 4; ++ks) {
      bf16x8 vb0 = *(const bf16x8*)&Vs[cur][q31 * 64 + sw[ks]];
      bf16x8 vb1 = *(const bf16x8*)&Vs[cur][(32 + q31) * 64 + sw[ks]];
      ctx0 = mfma32(pa[ks], vb0, ctx0);
      ctx1 = mfma32(pa[ks], vb1, ctx1);
    }
  }

  // epilogue: ctx D-frag row = q = crow(reg,hi), col = d = dchunk*32+(lane&31)
#pragma unroll
  for (int r = 0; r < 16; ++r) {
    const int q = (r & 3) + 8 * (r >> 2) + 4 * hi;
    const float inv = 1.f / lf[r];
    const size_t ro = (size_t)(b * S_ + qw + q) * D_ + h * HD_ + q31;
    O[ro]      = (bf16_t)(ctx0[r] * inv);
    O[ro + 32] = (bf16_t)(ctx1[r] * inv);
  }
}

// ---------------------------------------------------------------------------
// Kernel 4: out = LayerNorm(a + res) * g + b.  a,res bf16; g,b f32.
// ---------------------------------------------------------------------------
template <typename OUT>
__global__ __launch_bounds__(256) void add_ln_kernel(
    const bf16_t* __restrict__ a, const bf16_t* __restrict__ res,
    const float* __restrict__ g, const float* __restrict__ be,
    OUT* __restrict__ out) {
  const int t = threadIdx.x;
  const int d0 = t * 4;
  const size_t base = (size_t)blockIdx.x * D_ + d0;
  float x[4];
  float s1 = 0.f, s2 = 0.f;
#pragma unroll
  for (int e = 0; e < 4; ++e) {
    x[e] = (float)a[base + e] + (float)res[base + e];
    s1 += x[e];
    s2 += x[e] * x[e];
  }
#pragma unroll
  for (int o = 32; o > 0; o >>= 1) {
    s1 += __shfl_down(s1, o);
    s2 += __shfl_down(s2, o);
  }
  __shared__ float red[8];
  const int lane = t & 63, wid = t >> 6;
  if (lane == 0) { red[wid] = s1; red[4 + wid] = s2; }
  __syncthreads();
  if (t == 0) {
    float t1 = red[0] + red[1] + red[2] + red[3];
    float t2 = red[4] + red[5] + red[6] + red[7];
    float mu = t1 * (1.f / D_);
    float var = t2 * (1.f / D_) - mu * mu;
    red[0] = mu;
    red[1] = rsqrtf(var + 1e-5f);
  }
  __syncthreads();
  const float mu = red[0], rstd = red[1];
#pragma unroll
  for (int e = 0; e < 4; ++e)
    out[base + e] = (OUT)((x[e] - mu) * rstd * g[d0 + e] + be[d0 + e]);
}

// ---------------------------------------------------------------------------
extern "C" void kernel_launch(void* const* d_in, const int* in_sizes, int n_in,
                              void* d_out, int out_size, void* d_ws, size_t ws_size,
                              hipStream_t stream) {
  const float* key   = (const float*)d_in[0];
  const float* value = (const float*)d_in[1];
  const float* query = (const float*)d_in[2];
  const float* Wq = (const float*)d_in[3];
  const float* Wk = (const float*)d_in[4];
  const float* Wv = (const float*)d_in[5];
  const float* Wo = (const float*)d_in[6];
  const float* W1 = (const float*)d_in[7];
  const float* b1 = (const float*)d_in[8];
  const float* W2 = (const float*)d_in[9];
  const float* b2 = (const float*)d_in[10];
  const float* g1 = (const float*)d_in[11];
  const float* be1 = (const float*)d_in[12];
  const float* g2 = (const float*)d_in[13];
  const float* be2 = (const float*)d_in[14];
  float* out = (float*)d_out;

  bf16_t* ws = (bf16_t*)d_ws;
  const size_t NB = (size_t)B_ * S_ * D_;  // 4 Mi elems
  bf16_t* qpe = ws + 0 * NB;
  bf16_t* kpe = ws + 1 * NB;
  bf16_t* vpe = ws + 2 * NB;
  bf16_t* Qp  = ws + 3 * NB;
  bf16_t* Kp  = ws + 4 * NB;
  bf16_t* Vt  = ws + 5 * NB;   // [B][D][S] transposed V projection
  bf16_t* ctx = kpe;  // dead after QKV gemm
  bf16_t* ao  = vpe;  // dead after QKV gemm
  bf16_t* x1  = Qp;   // dead after attention
  bf16_t* hh  = Kp;   // dead after attention
  bf16_t* ff  = Vt;   // dead after attention

  // bf16 weights live in d_out (16 MB; 6 x 2 MB used, overwritten by final LN)
  bf16_t* wb = (bf16_t*)d_out;
  const size_t WN = (size_t)D_ * D_;
  bf16_t* Wqb = wb + 0 * WN;
  bf16_t* Wkb = wb + 1 * WN;
  bf16_t* Wvb = wb + 2 * WN;
  bf16_t* Wob = wb + 3 * WN;
  bf16_t* W1b = wb + 4 * WN;
  bf16_t* W2b = wb + 5 * WN;

  dim3 sgrid(D_ / 64, (B_ * S_) / 128);        // 16 x 32 = 512 (2/CU)

  cvtw_kernel<<<dim3(D_ * D_ / 1024, 6), 256, 0, stream>>>(
      Wq, Wk, Wv, Wo, W1, W2, wb);
  addpe_kernel<<<B_ * S_, 256, 0, stream>>>(query, key, value, qpe, kpe, vpe);

  gemm_qkv<<<dim3(D_ / 128, (B_ * S_) / 128, 3), 256, 0, stream>>>(
      qpe, kpe, vpe, Wqb, Wkb, Wvb, Qp, Kp, Vt);

  attn_kernel<<<dim3(S_ / 128, B_ * H_), 256, 0, stream>>>(Qp, Kp, Vt, ctx);

  gemm_s<0><<<sgrid, 256, 0, stream>>>(ctx, Wob, nullptr, ao);
  add_ln_kernel<bf16_t><<<B_ * S_, 256, 0, stream>>>(ao, qpe, g1, be1, x1);

  gemm_s<2><<<sgrid, 256, 0, stream>>>(x1, W1b, b1, hh);
  gemm_s<1><<<sgrid, 256, 0, stream>>>(hh, W2b, b2, ff);
  add_ln_kernel<float><<<B_ * S_, 256, 0, stream>>>(ff, x1, g2, be2, out);
}

// Round 9
// 223.371 us; speedup vs baseline: 1.1083x; 1.0857x over previous
//
#include <hip/hip_runtime.h>
#include <hip/hip_bf16.h>
#include <math.h>

// ---------------------------------------------------------------------------
// TransformerLayer: B=2 S=2048 D=1024 H=16 HD=64. I/O f32, internals bf16.
// Round 9: attention — K staged with swap23 row permutation so the PV
// A-fragment is lane-local (P-build = 16 cvt_pk, NO cross-lane exchange);
// s_setprio around MFMA clusters; add_ln loads/stores vectorized.
// ---------------------------------------------------------------------------

#define B_ 2
#define S_ 2048
#define D_ 1024
#define H_ 16
#define HD_ 64

typedef __bf16 bf16_t;
typedef __bf16 bf16x8 __attribute__((ext_vector_type(8)));
typedef __bf16 bf16x4v __attribute__((ext_vector_type(4)));
typedef float f32x4 __attribute__((ext_vector_type(4)));
typedef float f32x16 __attribute__((ext_vector_type(16)));
typedef unsigned int u32;

__device__ __forceinline__ f32x4 mfma16(bf16x8 a, bf16x8 b, f32x4 c) {
  return __builtin_amdgcn_mfma_f32_16x16x32_bf16(a, b, c, 0, 0, 0);
}
__device__ __forceinline__ f32x16 mfma32(bf16x8 a, bf16x8 b, f32x16 c) {
  return __builtin_amdgcn_mfma_f32_32x32x16_bf16(a, b, c, 0, 0, 0);
}
__device__ __forceinline__ u32 pkbf(float a, float b) {
  union { bf16_t h[2]; u32 u; } t;
  t.h[0] = (bf16_t)a; t.h[1] = (bf16_t)b;
  return t.u;
}

// global -> LDS direct copy, 16B/lane. LDS dest: wave-uniform base + lane*16.
__device__ __forceinline__ void gload_lds16(const bf16_t* g, bf16_t* l) {
  __builtin_amdgcn_global_load_lds((const __attribute__((address_space(1))) void*)g,
                                   (__attribute__((address_space(3))) void*)l,
                                   16, 0, 0);
}

// ---------------------------------------------------------------------------
// Kernel 0: convert 6 f32 weight matrices (D x D) to bf16, contiguous in dst.
// ---------------------------------------------------------------------------
__global__ __launch_bounds__(256) void cvtw_kernel(
    const float* __restrict__ w0, const float* __restrict__ w1,
    const float* __restrict__ w2, const float* __restrict__ w3,
    const float* __restrict__ w4, const float* __restrict__ w5,
    bf16_t* __restrict__ dst) {
  const int wsel = blockIdx.y;
  const float* src = wsel == 0 ? w0 : wsel == 1 ? w1 : wsel == 2 ? w2
                   : wsel == 3 ? w3 : wsel == 4 ? w4 : w5;
  const size_t off = (size_t)blockIdx.x * 1024 + threadIdx.x * 4;
  float4 v = *(const float4*)(src + off);
  bf16x4v r;
  r[0] = (bf16_t)v.x; r[1] = (bf16_t)v.y; r[2] = (bf16_t)v.z; r[3] = (bf16_t)v.w;
  *(bf16x4v*)(dst + (size_t)wsel * (D_ * D_) + off) = r;
}

// ---------------------------------------------------------------------------
// Kernel 1: positional encoding + add; f32 in -> bf16 out (q,k,v one pass).
// ---------------------------------------------------------------------------
__global__ __launch_bounds__(256) void addpe_kernel(
    const float* __restrict__ q, const float* __restrict__ k,
    const float* __restrict__ v,
    bf16_t* __restrict__ qo, bf16_t* __restrict__ ko, bf16_t* __restrict__ vo) {
  const int row = blockIdx.x;            // b*S + s
  const int s = row & (S_ - 1);
  const int d0 = threadIdx.x * 4;
  const size_t base = (size_t)row * D_ + d0;
  float pe[4];
#pragma unroll
  for (int p = 0; p < 2; ++p) {
    float div = __expf((float)(d0 + 2 * p) * -0.008994473019508f);
    float ang = (float)s * div;
    pe[2 * p]     = sinf(ang);
    pe[2 * p + 1] = cosf(ang);
  }
  float4 qv = *(const float4*)&q[base];
  float4 kv = *(const float4*)&k[base];
  float4 vv = *(const float4*)&v[base];
  bf16x4v qr, kr, vr;
  qr[0] = (bf16_t)(qv.x + pe[0]); qr[1] = (bf16_t)(qv.y + pe[1]);
  qr[2] = (bf16_t)(qv.z + pe[2]); qr[3] = (bf16_t)(qv.w + pe[3]);
  kr[0] = (bf16_t)(kv.x + pe[0]); kr[1] = (bf16_t)(kv.y + pe[1]);
  kr[2] = (bf16_t)(kv.z + pe[2]); kr[3] = (bf16_t)(kv.w + pe[3]);
  vr[0] = (bf16_t)(vv.x + pe[0]); vr[1] = (bf16_t)(vv.y + pe[1]);
  vr[2] = (bf16_t)(vv.z + pe[2]); vr[3] = (bf16_t)(vv.w + pe[3]);
  *(bf16x4v*)&qo[base] = qr;
  *(bf16x4v*)&ko[base] = kr;
  *(bf16x4v*)&vo[base] = vr;
}

// ---------------------------------------------------------------------------
// Kernel 2a: singles NT GEMM, tile 128x64 (grid 512 = 2 blocks/CU), BK=32,
// 4 waves (2x2, each 64x32), 2-phase dbuf, all-gload_lds.
// EPI: 0 plain, 1 +bias, 2 +bias+relu
// ---------------------------------------------------------------------------
template <int EPI>
__global__ __launch_bounds__(256) void gemm_s(
    const bf16_t* __restrict__ A, const bf16_t* __restrict__ Wb,
    const float* __restrict__ bias, bf16_t* __restrict__ C) {
  constexpr int Kd = 1024, NT = Kd / 32;
  __shared__ alignas(16) bf16_t As[2][128 * 32];
  __shared__ alignas(16) bf16_t Bs[2][64 * 32];
  const int t = threadIdx.x, lane = t & 63, wid = t >> 6;
  const int m0 = blockIdx.y * 128, n0 = blockIdx.x * 64;

  const bf16_t* Asrc0 = A + (size_t)(m0 + wid * 16 + (lane >> 2)) * Kd + (lane & 3) * 8;
  const bf16_t* Asrc1 = Asrc0 + (size_t)64 * Kd;
  const bf16_t* Wsrc = Wb + (size_t)(n0 + wid * 16 + (lane >> 2)) * Kd + (lane & 3) * 8;

  const f32x4 zero = {0.f, 0.f, 0.f, 0.f};
  f32x4 acc[4][2];
#pragma unroll
  for (int m = 0; m < 4; ++m) { acc[m][0] = zero; acc[m][1] = zero; }

  gload_lds16(Asrc0, &As[0][wid * 512]);
  gload_lds16(Asrc1, &As[0][2048 + wid * 512]);
  gload_lds16(Wsrc,  &Bs[0][wid * 512]);

  const int wr = wid >> 1, wc = wid & 1;
#pragma unroll 2
  for (int kt = 0; kt < NT; ++kt) {
    __syncthreads();
    const int cur = kt & 1, nxt = cur ^ 1;
    if (kt + 1 < NT) {
      const int k0 = (kt + 1) * 32;
      gload_lds16(Asrc0 + k0, &As[nxt][wid * 512]);
      gload_lds16(Asrc1 + k0, &As[nxt][2048 + wid * 512]);
      gload_lds16(Wsrc + k0,  &Bs[nxt][wid * 512]);
    }
    bf16x8 af[4], bfr[2];
#pragma unroll
    for (int m = 0; m < 4; ++m)
      af[m] = *(const bf16x8*)&As[cur][(wr * 64 + m * 16 + (lane & 15)) * 32 + (lane >> 4) * 8];
#pragma unroll
    for (int n = 0; n < 2; ++n)
      bfr[n] = *(const bf16x8*)&Bs[cur][(wc * 32 + n * 16 + (lane & 15)) * 32 + (lane >> 4) * 8];
    __builtin_amdgcn_s_setprio(1);
#pragma unroll
    for (int m = 0; m < 4; ++m)
#pragma unroll
      for (int n = 0; n < 2; ++n)
        acc[m][n] = mfma16(af[m], bfr[n], acc[m][n]);
    __builtin_amdgcn_s_setprio(0);
  }

  const int rbase = m0 + wr * 64 + (lane >> 4) * 4;
  const int cbase = n0 + wc * 32 + (lane & 15);
#pragma unroll
  for (int n = 0; n < 2; ++n) {
    const int col = cbase + n * 16;
    float bv = (EPI >= 1) ? bias[col] : 0.f;
#pragma unroll
    for (int m = 0; m < 4; ++m)
#pragma unroll
      for (int r = 0; r < 4; ++r) {
        float vv = acc[m][n][r] + bv;
        if (EPI == 2) vv = fmaxf(vv, 0.f);
        C[(size_t)(rbase + m * 16 + r) * D_ + col] = (bf16_t)vv;
      }
  }
}

// ---------------------------------------------------------------------------
// Kernel 2b: QKV batched GEMM, tile 128x128 (grid 768 = 3 blocks/CU), BK=32,
// 4 waves (2x2, each 64x64), 2-phase dbuf. z: 0=Q, 1=K, 2=V^T out.
// ---------------------------------------------------------------------------
__global__ __launch_bounds__(256) void gemm_qkv(
    const bf16_t* __restrict__ a0p, const bf16_t* __restrict__ a1p,
    const bf16_t* __restrict__ a2p,
    const bf16_t* __restrict__ w0p, const bf16_t* __restrict__ w1p,
    const bf16_t* __restrict__ w2p,
    bf16_t* __restrict__ o0, bf16_t* __restrict__ o1, bf16_t* __restrict__ o2) {
  constexpr int Kd = 1024, NT = Kd / 32;
  __shared__ alignas(16) bf16_t As[2][128 * 32];
  __shared__ alignas(16) bf16_t Bs[2][128 * 32];
  const int t = threadIdx.x, lane = t & 63, wid = t >> 6;
  const int g = lane >> 4, c16 = lane & 15;
  const int m0 = blockIdx.y * 128, n0 = blockIdx.x * 128;

  const bf16_t* A = a0p;
  const bf16_t* Wb = w0p;
  if (blockIdx.z == 1) { A = a1p; Wb = w1p; }
  else if (blockIdx.z == 2) { A = a2p; Wb = w2p; }

  const bf16_t* Asrc0 = A + (size_t)(m0 + wid * 16 + (lane >> 2)) * Kd + (lane & 3) * 8;
  const bf16_t* Asrc1 = Asrc0 + (size_t)64 * Kd;
  const bf16_t* Wsrc0 = Wb + (size_t)(n0 + wid * 16 + (lane >> 2)) * Kd + (lane & 3) * 8;
  const bf16_t* Wsrc1 = Wsrc0 + (size_t)64 * Kd;

  const f32x4 zero = {0.f, 0.f, 0.f, 0.f};
  f32x4 acc[4][4];
#pragma unroll
  for (int m = 0; m < 4; ++m)
#pragma unroll
    for (int n = 0; n < 4; ++n) acc[m][n] = zero;

  gload_lds16(Asrc0, &As[0][wid * 512]);
  gload_lds16(Asrc1, &As[0][2048 + wid * 512]);
  gload_lds16(Wsrc0, &Bs[0][wid * 512]);
  gload_lds16(Wsrc1, &Bs[0][2048 + wid * 512]);

  const int wr = wid >> 1, wc = wid & 1;
#pragma unroll 2
  for (int kt = 0; kt < NT; ++kt) {
    __syncthreads();
    const int cur = kt & 1, nxt = cur ^ 1;
    if (kt + 1 < NT) {
      const int k0 = (kt + 1) * 32;
      gload_lds16(Asrc0 + k0, &As[nxt][wid * 512]);
      gload_lds16(Asrc1 + k0, &As[nxt][2048 + wid * 512]);
      gload_lds16(Wsrc0 + k0, &Bs[nxt][wid * 512]);
      gload_lds16(Wsrc1 + k0, &Bs[nxt][2048 + wid * 512]);
    }
    bf16x8 af[4], bfr[4];
#pragma unroll
    for (int m = 0; m < 4; ++m)
      af[m] = *(const bf16x8*)&As[cur][(wr * 64 + m * 16 + c16) * 32 + g * 8];
#pragma unroll
    for (int n = 0; n < 4; ++n)
      bfr[n] = *(const bf16x8*)&Bs[cur][(wc * 64 + n * 16 + c16) * 32 + g * 8];
    __builtin_amdgcn_s_setprio(1);
#pragma unroll
    for (int m = 0; m < 4; ++m)
#pragma unroll
      for (int n = 0; n < 4; ++n)
        acc[m][n] = mfma16(af[m], bfr[n], acc[m][n]);
    __builtin_amdgcn_s_setprio(0);
  }

  const int rbase = m0 + wr * 64 + g * 4;
  const int cbase = n0 + wc * 64 + c16;
  if (blockIdx.z == 2) {
#pragma unroll
    for (int n = 0; n < 4; ++n) {
      const int col = cbase + n * 16;
#pragma unroll
      for (int m = 0; m < 4; ++m)
#pragma unroll
        for (int r = 0; r < 4; ++r) {
          const int row = rbase + m * 16 + r;
          const int bb = row >> 11, ss = row & (S_ - 1);
          o2[(size_t)bb * D_ * S_ + (size_t)col * S_ + ss] = (bf16_t)acc[m][n][r];
        }
    }
  } else {
    bf16_t* C = (blockIdx.z == 1) ? o1 : o0;
#pragma unroll
    for (int n = 0; n < 4; ++n) {
      const int col = cbase + n * 16;
#pragma unroll
      for (int m = 0; m < 4; ++m)
#pragma unroll
        for (int r = 0; r < 4; ++r)
          C[(size_t)(rbase + m * 16 + r) * D_ + col] = (bf16_t)acc[m][n][r];
    }
  }
}

// ---------------------------------------------------------------------------
// Kernel 3: flash attention, swapped-operand 32x32 MFMA, lane-local PV.
// grid (S/128, B*H), 4 waves x 32 q-rows, KVBLK=64.
// K is staged with row permutation swap23 (bits 2<->3 of row index) so that
// S^T reg r of lane (q,hi) holds key 16*(r>>3)+8*hi+4*((r>>2)&1)+(r&3);
// the PV A-frag elem (ks,hi,j) = key 16ks+8hi+j then sits at reg 8*(ks&1)+j
// of s0/s1 — P-build is 16 cvt_pk, zero shuffles. V columns stay natural.
// l via mfma-ones (crow layout = ctx layout). Swizzled gload_lds, dbuf.
// ---------------------------------------------------------------------------
__global__ __launch_bounds__(256) void attn_kernel(
    const bf16_t* __restrict__ Q, const bf16_t* __restrict__ K,
    const bf16_t* __restrict__ Vt, bf16_t* __restrict__ O) {
  constexpr int NT = S_ / 64;
  constexpr float THR = 11.5416f;          // 8 * log2(e)
  __shared__ alignas(16) bf16_t Ks[2][64 * 64];
  __shared__ alignas(16) bf16_t Vs[2][64 * 64];
  const int t = threadIdx.x, lane = t & 63, wid = t >> 6;
  const int b = blockIdx.y >> 4, h = blockIdx.y & 15;
  const int qw = blockIdx.x * 128 + wid * 32;   // this wave's 32 q-rows
  const int q31 = lane & 31, hi = lane >> 5;

  // Q as B-operand frags: col=lane&31=q, k=hi*8+j = d within 16-slice.
  bf16x8 qb[4];
  {
    const size_t qrow = (size_t)(b * S_ + qw + q31) * D_ + h * HD_ + hi * 8;
#pragma unroll
    for (int ksl = 0; ksl < 4; ++ksl) {
      bf16x8 v = *(const bf16x8*)&Q[qrow + ksl * 16];
#pragma unroll
      for (int j = 0; j < 8; ++j)
        v[j] = (bf16_t)((float)v[j] * (0.125f * 1.44269504f));
      qb[ksl] = v;
    }
  }
  bf16x8 onesb;
#pragma unroll
  for (int j = 0; j < 8; ++j) onesb[j] = (bf16_t)1.0f;

  f32x16 ctx0 = {0.f,0.f,0.f,0.f,0.f,0.f,0.f,0.f,0.f,0.f,0.f,0.f,0.f,0.f,0.f,0.f};
  f32x16 ctx1 = ctx0, lf = ctx0;
  float mrow = -1e30f;

  // swizzled LDS read slots: slot x at row r -> phys (x^(r&7))*8.
  int sw[4];
#pragma unroll
  for (int x = 0; x < 4; ++x) sw[x] = ((x * 2 + hi) ^ (q31 & 7)) * 8;

  // staging: wave w, chunk c covers LDS tile-rows c*32 + w*8 + (lane>>3);
  // phys slot (lane&7) holds logical slot (lane&7)^(row&7).
  // K global row = swap23(LDS row) (key permutation, algebra-neutral).
  const int trow = wid * 8 + (lane >> 3);
  const int krow_g = (trow & ~12) | ((trow & 4) << 1) | ((trow & 8) >> 1);
  const int lslot = ((lane & 7) ^ ((lane >> 3) & 7)) * 8;
  const bf16_t* Ksrc0 = K + (size_t)(b * S_ + krow_g) * D_ + h * HD_ + lslot;
  const bf16_t* Ksrc1 = K + (size_t)(b * S_ + 32 + krow_g) * D_ + h * HD_ + lslot;
  const bf16_t* Vsrc0 = Vt + (size_t)b * D_ * S_ + (size_t)(h * HD_ + trow) * S_ + lslot;
  const bf16_t* Vsrc1 = Vt + (size_t)b * D_ * S_ + (size_t)(h * HD_ + 32 + trow) * S_ + lslot;

  gload_lds16(Ksrc0, &Ks[0][wid * 512]);
  gload_lds16(Ksrc1, &Ks[0][2048 + wid * 512]);
  gload_lds16(Vsrc0, &Vs[0][wid * 512]);
  gload_lds16(Vsrc1, &Vs[0][2048 + wid * 512]);

#pragma unroll 2
  for (int kt = 0; kt < NT; ++kt) {
    __syncthreads();                       // tile kt resident
    const int cur = kt & 1, nxt = cur ^ 1;
    if (kt + 1 < NT) {
      const size_t ko = (size_t)(kt + 1) * 64 * D_;
      gload_lds16(Ksrc0 + ko, &Ks[nxt][wid * 512]);
      gload_lds16(Ksrc1 + ko, &Ks[nxt][2048 + wid * 512]);
      const size_t vo = (size_t)(kt + 1) * 64;
      gload_lds16(Vsrc0 + vo, &Vs[nxt][wid * 512]);
      gload_lds16(Vsrc1 + vo, &Vs[nxt][2048 + wid * 512]);
    }

    // QK^T swapped: s0 = keys(LDS rows 0..31), s1 = rows 32..63
    f32x16 s0 = {0.f,0.f,0.f,0.f,0.f,0.f,0.f,0.f,0.f,0.f,0.f,0.f,0.f,0.f,0.f,0.f};
    f32x16 s1 = s0;
    __builtin_amdgcn_s_setprio(1);
#pragma unroll
    for (int ksl = 0; ksl < 4; ++ksl) {
      bf16x8 kb0 = *(const bf16x8*)&Ks[cur][q31 * 64 + sw[ksl]];
      bf16x8 kb1 = *(const bf16x8*)&Ks[cur][(32 + q31) * 64 + sw[ksl]];
      s0 = mfma32(kb0, qb[ksl], s0);
      s1 = mfma32(kb1, qb[ksl], s1);
    }
    __builtin_amdgcn_s_setprio(0);

    // lane-local softmax for q = lane&31 (keys split with partner lane^32)
    float mt = fmaxf(s0[0], s1[0]);
#pragma unroll
    for (int r = 1; r < 16; ++r) mt = fmaxf(mt, fmaxf(s0[r], s1[r]));
    mt = fmaxf(mt, __shfl_xor(mt, 32));
    if (__any(mt > mrow + THR)) {
      float mnew = fmaxf(mrow, mt);
      float scl = exp2f(mrow - mnew);
      mrow = mnew;
#pragma unroll
      for (int r = 0; r < 16; ++r) {
        float sc = __shfl(scl, (r & 3) + 8 * (r >> 2) + 4 * hi);
        ctx0[r] *= sc; ctx1[r] *= sc; lf[r] *= sc;
      }
    }
    // P = exp2(s - m) in place
#pragma unroll
    for (int r = 0; r < 16; ++r) {
      s0[r] = exp2f(s0[r] - mrow);
      s1[r] = exp2f(s1[r] - mrow);
    }

    // PV A-frags, lane-local: pa[ks] = pack of regs 8*(ks&1)..+7 of s0/s1
    bf16x8 pa[4];
#pragma unroll
    for (int ks = 0; ks < 4; ++ks) {
      union { u32 w[4]; bf16x8 v; } u;
      if (ks < 2) {
#pragma unroll
        for (int w = 0; w < 4; ++w)
          u.w[w] = pkbf(s0[(ks & 1) * 8 + 2 * w], s0[(ks & 1) * 8 + 2 * w + 1]);
      } else {
#pragma unroll
        for (int w = 0; w < 4; ++w)
          u.w[w] = pkbf(s1[(ks & 1) * 8 + 2 * w], s1[(ks & 1) * 8 + 2 * w + 1]);
      }
      pa[ks] = u.v;
    }

    // l and PV: rows = q (crow layout), cols = d
    __builtin_amdgcn_s_setprio(1);
#pragma unroll
    for (int ks = 0; ks < 4; ++ks) lf = mfma32(pa[ks], onesb, lf);
#pragma unroll
    for (int ks = 0; ks < 4; ++ks) {
      bf16x8 vb0 = *(const bf16x8*)&Vs[cur][q31 * 64 + sw[ks]];
      bf16x8 vb1 = *(const bf16x8*)&Vs[cur][(32 + q31) * 64 + sw[ks]];
      ctx0 = mfma32(pa[ks], vb0, ctx0);
      ctx1 = mfma32(pa[ks], vb1, ctx1);
    }
    __builtin_amdgcn_s_setprio(0);
  }

  // epilogue: ctx D-frag row = q = crow(reg,hi), col = d = dchunk*32+(lane&31)
#pragma unroll
  for (int r = 0; r < 16; ++r) {
    const int q = (r & 3) + 8 * (r >> 2) + 4 * hi;
    const float inv = 1.f / lf[r];
    const size_t ro = (size_t)(b * S_ + qw + q) * D_ + h * HD_ + q31;
    O[ro]      = (bf16_t)(ctx0[r] * inv);
    O[ro + 32] = (bf16_t)(ctx1[r] * inv);
  }
}

// ---------------------------------------------------------------------------
// Kernel 4: out = LayerNorm(a + res) * g + b.  a,res bf16; g,b f32.
// ---------------------------------------------------------------------------
template <typename OUT>
__global__ __launch_bounds__(256) void add_ln_kernel(
    const bf16_t* __restrict__ a, const bf16_t* __restrict__ res,
    const float* __restrict__ g, const float* __restrict__ be,
    OUT* __restrict__ out) {
  const int t = threadIdx.x;
  const int d0 = t * 4;
  const size_t base = (size_t)blockIdx.x * D_ + d0;
  bf16x4v av = *(const bf16x4v*)&a[base];
  bf16x4v rv = *(const bf16x4v*)&res[base];
  float x[4];
  float s1 = 0.f, s2 = 0.f;
#pragma unroll
  for (int e = 0; e < 4; ++e) {
    x[e] = (float)av[e] + (float)rv[e];
    s1 += x[e];
    s2 += x[e] * x[e];
  }
#pragma unroll
  for (int o = 32; o > 0; o >>= 1) {
    s1 += __shfl_down(s1, o);
    s2 += __shfl_down(s2, o);
  }
  __shared__ float red[8];
  const int lane = t & 63, wid = t >> 6;
  if (lane == 0) { red[wid] = s1; red[4 + wid] = s2; }
  __syncthreads();
  if (t == 0) {
    float t1 = red[0] + red[1] + red[2] + red[3];
    float t2 = red[4] + red[5] + red[6] + red[7];
    float mu = t1 * (1.f / D_);
    float var = t2 * (1.f / D_) - mu * mu;
    red[0] = mu;
    red[1] = rsqrtf(var + 1e-5f);
  }
  __syncthreads();
  const float mu = red[0], rstd = red[1];
  const float4 gv = *(const float4*)&g[d0];
  const float4 bv = *(const float4*)&be[d0];
  float y[4];
  y[0] = (x[0] - mu) * rstd * gv.x + bv.x;
  y[1] = (x[1] - mu) * rstd * gv.y + bv.y;
  y[2] = (x[2] - mu) * rstd * gv.z + bv.z;
  y[3] = (x[3] - mu) * rstd * gv.w + bv.w;
  if constexpr (sizeof(OUT) == 2) {
    bf16x4v o;
    o[0] = (bf16_t)y[0]; o[1] = (bf16_t)y[1]; o[2] = (bf16_t)y[2]; o[3] = (bf16_t)y[3];
    *(bf16x4v*)&out[base] = o;
  } else {
    float4 o = {y[0], y[1], y[2], y[3]};
    *(float4*)&out[base] = o;
  }
}

// ---------------------------------------------------------------------------
extern "C" void kernel_launch(void* const* d_in, const int* in_sizes, int n_in,
                              void* d_out, int out_size, void* d_ws, size_t ws_size,
                              hipStream_t stream) {
  const float* key   = (const float*)d_in[0];
  const float* value = (const float*)d_in[1];
  const float* query = (const float*)d_in[2];
  const float* Wq = (const float*)d_in[3];
  const float* Wk = (const float*)d_in[4];
  const float* Wv = (const float*)d_in[5];
  const float* Wo = (const float*)d_in[6];
  const float* W1 = (const float*)d_in[7];
  const float* b1 = (const float*)d_in[8];
  const float* W2 = (const float*)d_in[9];
  const float* b2 = (const float*)d_in[10];
  const float* g1 = (const float*)d_in[11];
  const float* be1 = (const float*)d_in[12];
  const float* g2 = (const float*)d_in[13];
  const float* be2 = (const float*)d_in[14];
  float* out = (float*)d_out;

  bf16_t* ws = (bf16_t*)d_ws;
  const size_t NB = (size_t)B_ * S_ * D_;  // 4 Mi elems
  bf16_t* qpe = ws + 0 * NB;
  bf16_t* kpe = ws + 1 * NB;
  bf16_t* vpe = ws + 2 * NB;
  bf16_t* Qp  = ws + 3 * NB;
  bf16_t* Kp  = ws + 4 * NB;
  bf16_t* Vt  = ws + 5 * NB;   // [B][D][S] transposed V projection
  bf16_t* ctx = kpe;  // dead after QKV gemm
  bf16_t* ao  = vpe;  // dead after QKV gemm
  bf16_t* x1  = Qp;   // dead after attention
  bf16_t* hh  = Kp;   // dead after attention
  bf16_t* ff  = Vt;   // dead after attention

  // bf16 weights live in d_out (16 MB; 6 x 2 MB used, overwritten by final LN)
  bf16_t* wb = (bf16_t*)d_out;
  const size_t WN = (size_t)D_ * D_;
  bf16_t* Wqb = wb + 0 * WN;
  bf16_t* Wkb = wb + 1 * WN;
  bf16_t* Wvb = wb + 2 * WN;
  bf16_t* Wob = wb + 3 * WN;
  bf16_t* W1b = wb + 4 * WN;
  bf16_t* W2b = wb + 5 * WN;

  dim3 sgrid(D_ / 64, (B_ * S_) / 128);        // 16 x 32 = 512 (2/CU)

  cvtw_kernel<<<dim3(D_ * D_ / 1024, 6), 256, 0, stream>>>(
      Wq, Wk, Wv, Wo, W1, W2, wb);
  addpe_kernel<<<B_ * S_, 256, 0, stream>>>(query, key, value, qpe, kpe, vpe);

  gemm_qkv<<<dim3(D_ / 128, (B_ * S_) / 128, 3), 256, 0, stream>>>(
      qpe, kpe, vpe, Wqb, Wkb, Wvb, Qp, Kp, Vt);

  attn_kernel<<<dim3(S_ / 128, B_ * H_), 256, 0, stream>>>(Qp, Kp, Vt, ctx);

  gemm_s<0><<<sgrid, 256, 0, stream>>>(ctx, Wob, nullptr, ao);
  add_ln_kernel<bf16_t><<<B_ * S_, 256, 0, stream>>>(ao, qpe, g1, be1, x1);

  gemm_s<2><<<sgrid, 256, 0, stream>>>(x1, W1b, b1, hh);
  gemm_s<1><<<sgrid, 256, 0, stream>>>(hh, W2b, b2, ff);
  add_ln_kernel<float><<<B_ * S_, 256, 0, stream>>>(ff, x1, g2, be2, out);
}